// Round 6
// baseline (122.750 us; speedup 1.0000x reference)
//
#include <hip/hip_runtime.h>

#define HW (512 * 512)

typedef float vfloat4 __attribute__((ext_vector_type(4)));

constexpr int TX = 64, TY = 32;       // pixel tile per block; 256 threads x (8x1 px strip)
constexpr int CWP = 67;               // LDS row stride for 66-wide halo tile (+1 pad)
constexpr float BWIDTH = 1.0f / 15.0f;
constexpr float DELTA = 3e-5f;        // guard >= ~2.5x the 1.2e-5 fast-path error bound

__global__ __launch_bounds__(256) void nectar_binning_kernel(
    const float* __restrict__ logits,      // [16,4,512,512]
    const float* __restrict__ val_freqs,   // [4,9,15]
    float* __restrict__ out)               // [16,4,512,512]
{
    // one-hot nibble pack per halo cell: 1u<<(4*class), 0 for out-of-bounds
    __shared__ unsigned int cls[34 * CWP];
    __shared__ float vf[540];

    const int b  = blockIdx.z;
    const int w0 = blockIdx.x * TX;
    const int h0 = blockIdx.y * TY;
    const int tid = threadIdx.x;

    for (int i = tid; i < 540; i += 256) vf[i] = val_freqs[i];

    const float* lb = logits + (size_t)b * 4 * HW;

    const int tix = tid & 7;           // strip col (8 strips of 8 px)
    const int tiy = tid >> 3;          // row (32 rows)
    const int w = w0 + 8 * tix;
    const int h = h0 + tiy;
    const int base = (h << 9) + w;

    // ---- all global loads first: maximize loads in flight (128 B/lane interior) ----
    float xv[4][8];  // [class][px]
    #pragma unroll
    for (int c = 0; c < 4; c++) {
        vfloat4 v0 = *reinterpret_cast<const vfloat4*>(lb + (size_t)c * HW + base);
        vfloat4 v1 = *reinterpret_cast<const vfloat4*>(lb + (size_t)c * HW + base + 4);
        xv[c][0] = v0.x; xv[c][1] = v0.y; xv[c][2] = v0.z; xv[c][3] = v0.w;
        xv[c][4] = v1.x; xv[c][5] = v1.y; xv[c][6] = v1.z; xv[c][7] = v1.w;
    }

    // border ring of the 34x66 halo: 196 cells, one predicated pass
    bool ring = tid < 196;
    int rly, rlx;
    if (tid < 66)       { rly = 0;         rlx = tid;       }
    else if (tid < 132) { rly = 33;        rlx = tid - 66;  }
    else if (tid < 164) { rly = tid - 131; rlx = 0;         }
    else                { rly = tid - 163; rlx = 65;        }
    unsigned int rv = 0;
    if (ring) {
        int hh = h0 + rly - 1;
        int ww = w0 + rlx - 1;
        if ((unsigned)hh < 512u && (unsigned)ww < 512u) {
            int bb = (hh << 9) + ww;
            float x0 = lb[bb];
            float x1 = lb[HW + bb];
            float x2 = lb[2 * HW + bb];
            float x3 = lb[3 * HW + bb];
            int c = 0; float best = x0;
            if (x1 > best) { best = x1; c = 1; }
            if (x2 > best) { best = x2; c = 2; }
            if (x3 > best) { best = x3; c = 3; }
            rv = 1u << (4 * c);
        }
        cls[rly * CWP + rlx] = rv;
    }

    // ---- own 8 pixels: ONE logit read feeds argmax AND bins ----
    unsigned int pbin[8];  // per px: 4 bins packed 4 bits each
    #pragma unroll
    for (int j = 0; j < 8; j++) {
        float x0 = xv[0][j], x1 = xv[1][j], x2 = xv[2][j], x3 = xv[3][j];
        // argmax(logits) == argmax(softmax), first-index tie-break (bit-exact since R2)
        int c = 0; float best = x0;
        if (x1 > best) { best = x1; c = 1; }
        if (x2 > best) { best = x2; c = 2; }
        if (x3 > best) { best = x3; c = 3; }
        cls[(tiy + 1) * CWP + 1 + 8 * tix + j] = 1u << (4 * c);

        float m = fmaxf(fmaxf(x0, x1), fmaxf(x2, x3));
        float t0 = x0 - m, t1 = x1 - m, t2 = x2 - m, t3 = x3 - m;
        // fast path: native exp + rcp; |q_fast - q_exact| <= ~1.2e-5 << DELTA
        float f0 = __expf(t0), f1 = __expf(t1), f2 = __expf(t2), f3 = __expf(t3);
        float sf = ((f0 + f1) + f2) + f3;
        float rs = __builtin_amdgcn_rcpf(sf);
        float q[4];
        q[0] = (f0 * rs) * 15.0f; q[1] = (f1 * rs) * 15.0f;
        q[2] = (f2 * rs) * 15.0f; q[3] = (f3 * rs) * 15.0f;
        int bin[4];
        bool slow = false;
        #pragma unroll
        for (int c2 = 0; c2 < 4; c2++) {
            bin[c2] = (int)q[c2];                 // q >= 0: trunc == floor
            float fr = q[c2] - (float)bin[c2];
            slow |= (fr < DELTA) | (fr > 1.0f - DELTA);
        }
        if (slow) {  // exact ocml-exp + IEEE-divide chain (matches np: absmax 0 in R2-R5)
            float e0 = expf(t0), e1 = expf(t1), e2 = expf(t2), e3 = expf(t3);
            float s = ((e0 + e1) + e2) + e3;
            bin[0] = (int)((e0 / s) / BWIDTH); bin[1] = (int)((e1 / s) / BWIDTH);
            bin[2] = (int)((e2 / s) / BWIDTH); bin[3] = (int)((e3 / s) / BWIDTH);
        }
        unsigned int pb = 0;
        #pragma unroll
        for (int c2 = 0; c2 < 4; c2++) {
            int bc = bin[c2] > 14 ? 14 : bin[c2];
            pb |= (unsigned int)bc << (4 * c2);
        }
        pbin[j] = pb;
    }
    __syncthreads();

    // ---- neighbor counts + gather + normalize + store ----
    const unsigned int* p0 = &cls[tiy * CWP + 8 * tix];
    unsigned int r1[10], colsum[10];
    #pragma unroll
    for (int j = 0; j < 10; j++) {
        unsigned int a    = p0[j];
        unsigned int bmid = p0[CWP + j];
        unsigned int cbot = p0[2 * CWP + j];
        r1[j] = bmid;
        colsum[j] = a + bmid + cbot;
    }

    float res[4][8];  // [class][px]
    #pragma unroll
    for (int j = 0; j < 8; j++) {
        unsigned int pk = colsum[j] + colsum[j + 1] + colsum[j + 2] - r1[j + 1];
        unsigned int pb = pbin[j];
        float cs = 0.0f;
        float cal[4];
        #pragma unroll
        for (int c = 0; c < 4; c++) {
            int cnt = (int)((pk >> (4 * c)) & 0xFu);   // [0,8]
            int bin = (int)((pb >> (4 * c)) & 0xFu);   // [0,14]
            float v = vf[c * 135 + cnt * 15 + bin];
            cal[c] = v;
            cs += v;                                   // ref class order
        }
        if (cs == 0.0f) cs = 1.0f;
        float inv = __builtin_amdgcn_rcpf(cs);         // tolerance 1.97e-2 >> 1 ULP
        #pragma unroll
        for (int c = 0; c < 4; c++) res[c][j] = cal[c] * inv;
    }

    float* ob = out + (size_t)b * 4 * HW + base;
    #pragma unroll
    for (int c = 0; c < 4; c++) {
        vfloat4 v0, v1;
        v0.x = res[c][0]; v0.y = res[c][1]; v0.z = res[c][2]; v0.w = res[c][3];
        v1.x = res[c][4]; v1.y = res[c][5]; v1.z = res[c][6]; v1.w = res[c][7];
        __builtin_nontemporal_store(v0, reinterpret_cast<vfloat4*>(ob + (size_t)c * HW));
        __builtin_nontemporal_store(v1, reinterpret_cast<vfloat4*>(ob + (size_t)c * HW + 4));
    }
}

extern "C" void kernel_launch(void* const* d_in, const int* in_sizes, int n_in,
                              void* d_out, int out_size, void* d_ws, size_t ws_size,
                              hipStream_t stream) {
    const float* logits    = (const float*)d_in[0];
    const float* val_freqs = (const float*)d_in[1];
    float* out             = (float*)d_out;

    dim3 block(256, 1, 1);
    dim3 grid(512 / TX, 512 / TY, 16);
    hipLaunchKernelGGL(nectar_binning_kernel, grid, block, 0, stream,
                       logits, val_freqs, out);
}

// Round 7
// 120.475 us; speedup vs baseline: 1.0189x; 1.0189x over previous
//
#include <hip/hip_runtime.h>

#define HW (512 * 512)

typedef float vfloat4 __attribute__((ext_vector_type(4)));
typedef unsigned int vuint4 __attribute__((ext_vector_type(4)));

constexpr float BWIDTH = 1.0f / 15.0f;
constexpr float DELTA = 3e-5f;        // guard >= ~2.5x the 1.2e-5 fast-path error bound

// ---------------- K1: per-pixel class + bins -> packed u32 [B,H,W] ----------------
// word: bits[15:0] = 4 bins x 4b; bits[31:16] = one-hot class nibble (1 << (16+4c))
__global__ __launch_bounds__(256) void k1_classbins(
    const float* __restrict__ logits, unsigned int* __restrict__ packed)
{
    const int g  = (blockIdx.x * 256 + threadIdx.x) * 4;  // linear px over [16*HW)
    const int b  = g >> 18;                               // / HW
    const int hw = g & (HW - 1);
    const float* lb = logits + (size_t)b * 4 * HW + hw;

    vfloat4 v[4];
    #pragma unroll
    for (int c = 0; c < 4; c++)
        v[c] = *reinterpret_cast<const vfloat4*>(lb + (size_t)c * HW);

    vuint4 outw;
    #pragma unroll
    for (int j = 0; j < 4; j++) {
        float x0 = v[0][j], x1 = v[1][j], x2 = v[2][j], x3 = v[3][j];
        // argmax(logits) == argmax(softmax), first-index tie-break (bit-exact R2-R6)
        int c = 0; float best = x0;
        if (x1 > best) { best = x1; c = 1; }
        if (x2 > best) { best = x2; c = 2; }
        if (x3 > best) { best = x3; c = 3; }

        float m = fmaxf(fmaxf(x0, x1), fmaxf(x2, x3));
        float t0 = x0 - m, t1 = x1 - m, t2 = x2 - m, t3 = x3 - m;
        // fast path: native exp + rcp; |q_fast - q_exact| <= ~1.2e-5 << DELTA
        float f0 = __expf(t0), f1 = __expf(t1), f2 = __expf(t2), f3 = __expf(t3);
        float sf = ((f0 + f1) + f2) + f3;
        float rs = __builtin_amdgcn_rcpf(sf);
        float q[4] = { (f0 * rs) * 15.0f, (f1 * rs) * 15.0f,
                       (f2 * rs) * 15.0f, (f3 * rs) * 15.0f };
        int bin[4];
        bool slow = false;
        #pragma unroll
        for (int c2 = 0; c2 < 4; c2++) {
            bin[c2] = (int)q[c2];                  // q >= 0: trunc == floor
            float fr = q[c2] - (float)bin[c2];
            slow |= (fr < DELTA) | (fr > 1.0f - DELTA);
        }
        if (slow) {  // exact ocml-exp + IEEE-divide chain (matches np bit-for-bit)
            float e0 = expf(t0), e1 = expf(t1), e2 = expf(t2), e3 = expf(t3);
            float s = ((e0 + e1) + e2) + e3;
            bin[0] = (int)((e0 / s) / BWIDTH); bin[1] = (int)((e1 / s) / BWIDTH);
            bin[2] = (int)((e2 / s) / BWIDTH); bin[3] = (int)((e3 / s) / BWIDTH);
        }
        unsigned int wv = 1u << (16 + 4 * c);
        #pragma unroll
        for (int c2 = 0; c2 < 4; c2++) {
            int bc = bin[c2] > 14 ? 14 : bin[c2];
            wv |= (unsigned int)bc << (4 * c2);
        }
        outw[j] = wv;
    }
    // plain store: K2 re-reads this; 16 MB fits L2/L3
    *reinterpret_cast<vuint4*>(packed + g) = outw;
}

// ---------------- K2: 3x3 counts + gather + normalize -> out ----------------
__global__ __launch_bounds__(256) void k2_gather(
    const unsigned int* __restrict__ packed, const float* __restrict__ val_freqs,
    float* __restrict__ out)
{
    __shared__ float vf[540];
    const int tid = threadIdx.x;
    for (int i = tid; i < 540; i += 256) vf[i] = val_freqs[i];
    __syncthreads();

    const int b  = blockIdx.z;
    const int y0 = blockIdx.x * 4;          // 4-row band
    const int x  = (tid & 127) * 4;         // 4-px strip, full 512-wide rows
    const int r  = y0 + (tid >> 7) * 2;     // own rows r, r+1

    const unsigned int* pb = packed + (size_t)b * HW;

    // rows r-1 .. r+2, cols x-1 .. x+4 (zeros outside the image)
    unsigned int cell[4][6];
    #pragma unroll
    for (int k = 0; k < 4; k++) {
        int rr = r - 1 + k;
        if ((unsigned)rr < 512u) {
            const unsigned int* rp = pb + (rr << 9) + x;
            vuint4 vv = *reinterpret_cast<const vuint4*>(rp);
            cell[k][1] = vv.x; cell[k][2] = vv.y; cell[k][3] = vv.z; cell[k][4] = vv.w;
            cell[k][0] = (x == 0)   ? 0u : rp[-1];
            cell[k][5] = (x == 508) ? 0u : rp[4];
        } else {
            #pragma unroll
            for (int j = 0; j < 6; j++) cell[k][j] = 0u;
        }
    }

    // vertical one-hot column sums for the two own rows
    unsigned int colsum[2][6];
    #pragma unroll
    for (int j = 0; j < 6; j++) {
        unsigned int a0 = cell[0][j] >> 16, a1 = cell[1][j] >> 16;
        unsigned int a2 = cell[2][j] >> 16, a3 = cell[3][j] >> 16;
        unsigned int mid = a1 + a2;
        colsum[0][j] = mid + a0;
        colsum[1][j] = mid + a3;
    }

    float* ob = out + (size_t)b * 4 * HW;
    #pragma unroll
    for (int k = 0; k < 2; k++) {           // own row r+k
        float resv[4][4];                   // [class][px]
        #pragma unroll
        for (int j = 0; j < 4; j++) {
            unsigned int own = cell[k + 1][j + 1];
            unsigned int pk  = colsum[k][j] + colsum[k][j + 1] + colsum[k][j + 2]
                             - (own >> 16); // exclude center
            float cs = 0.0f;
            float cal[4];
            #pragma unroll
            for (int c = 0; c < 4; c++) {
                int cnt = (int)((pk  >> (4 * c)) & 0xFu);   // [0,8]
                int bin = (int)((own >> (4 * c)) & 0xFu);   // [0,14]
                float vv = vf[c * 135 + cnt * 15 + bin];
                cal[c] = vv;
                cs += vv;                                   // ref class order
            }
            if (cs == 0.0f) cs = 1.0f;
            float inv = __builtin_amdgcn_rcpf(cs);          // tolerance 1.97e-2 >> 1 ULP
            #pragma unroll
            for (int c = 0; c < 4; c++) resv[c][j] = cal[c] * inv;
        }
        int basew = ((r + k) << 9) + x;
        #pragma unroll
        for (int c = 0; c < 4; c++) {
            vfloat4 vo;
            vo.x = resv[c][0]; vo.y = resv[c][1]; vo.z = resv[c][2]; vo.w = resv[c][3];
            __builtin_nontemporal_store(vo, reinterpret_cast<vfloat4*>(ob + (size_t)c * HW + basew));
        }
    }
}

// ---------------- fallback: proven R5 fused kernel (if ws too small) ----------------
constexpr int FTX = 64, FTY = 16;
constexpr int CWP = 67;

__global__ __launch_bounds__(256) void fused_fallback(
    const float* __restrict__ logits, const float* __restrict__ val_freqs,
    float* __restrict__ out)
{
    __shared__ unsigned int cls[18 * CWP];
    __shared__ float vf[540];
    const int b  = blockIdx.z;
    const int w0 = blockIdx.x * FTX;
    const int h0 = blockIdx.y * FTY;
    const int tid = threadIdx.x;
    for (int i = tid; i < 540; i += 256) vf[i] = val_freqs[i];
    const float* lb = logits + (size_t)b * 4 * HW;
    const int tix = tid & 15, tiy = tid >> 4;
    const int w = w0 + 4 * tix, h = h0 + tiy;
    const int base = (h << 9) + w;
    float xv[4][4];
    #pragma unroll
    for (int c = 0; c < 4; c++) {
        vfloat4 v = *reinterpret_cast<const vfloat4*>(lb + (size_t)c * HW + base);
        xv[c][0] = v.x; xv[c][1] = v.y; xv[c][2] = v.z; xv[c][3] = v.w;
    }
    unsigned int pbin[4];
    #pragma unroll
    for (int j = 0; j < 4; j++) {
        float x0 = xv[0][j], x1 = xv[1][j], x2 = xv[2][j], x3 = xv[3][j];
        int c = 0; float best = x0;
        if (x1 > best) { best = x1; c = 1; }
        if (x2 > best) { best = x2; c = 2; }
        if (x3 > best) { best = x3; c = 3; }
        cls[(tiy + 1) * CWP + 1 + 4 * tix + j] = 1u << (4 * c);
        float m = fmaxf(fmaxf(x0, x1), fmaxf(x2, x3));
        float t0 = x0 - m, t1 = x1 - m, t2 = x2 - m, t3 = x3 - m;
        float f0 = __expf(t0), f1 = __expf(t1), f2 = __expf(t2), f3 = __expf(t3);
        float sf = ((f0 + f1) + f2) + f3;
        float rs = __builtin_amdgcn_rcpf(sf);
        float q[4] = {(f0*rs)*15.0f,(f1*rs)*15.0f,(f2*rs)*15.0f,(f3*rs)*15.0f};
        int bin[4]; bool slow = false;
        #pragma unroll
        for (int c2 = 0; c2 < 4; c2++) {
            bin[c2] = (int)q[c2];
            float fr = q[c2] - (float)bin[c2];
            slow |= (fr < DELTA) | (fr > 1.0f - DELTA);
        }
        if (slow) {
            float e0 = expf(t0), e1 = expf(t1), e2 = expf(t2), e3 = expf(t3);
            float s = ((e0 + e1) + e2) + e3;
            bin[0]=(int)((e0/s)/BWIDTH); bin[1]=(int)((e1/s)/BWIDTH);
            bin[2]=(int)((e2/s)/BWIDTH); bin[3]=(int)((e3/s)/BWIDTH);
        }
        unsigned int pbv = 0;
        #pragma unroll
        for (int c2 = 0; c2 < 4; c2++) {
            int bc = bin[c2] > 14 ? 14 : bin[c2];
            pbv |= (unsigned int)bc << (4 * c2);
        }
        pbin[j] = pbv;
    }
    if (tid < 164) {
        int ly, lx;
        if (tid < 66)       { ly = 0;         lx = tid;      }
        else if (tid < 132) { ly = 17;        lx = tid - 66; }
        else if (tid < 148) { ly = tid - 131; lx = 0;        }
        else                { ly = tid - 147; lx = 65;       }
        int hh = h0 + ly - 1, ww = w0 + lx - 1;
        unsigned int v = 0;
        if ((unsigned)hh < 512u && (unsigned)ww < 512u) {
            int bb = (hh << 9) + ww;
            float x0 = lb[bb], x1 = lb[HW + bb], x2 = lb[2*HW + bb], x3 = lb[3*HW + bb];
            int c = 0; float best = x0;
            if (x1 > best) { best = x1; c = 1; }
            if (x2 > best) { best = x2; c = 2; }
            if (x3 > best) { best = x3; c = 3; }
            v = 1u << (4 * c);
        }
        cls[ly * CWP + lx] = v;
    }
    __syncthreads();
    const unsigned int* p0 = &cls[tiy * CWP + 4 * tix];
    unsigned int r1[6], colsum[6];
    #pragma unroll
    for (int j = 0; j < 6; j++) {
        unsigned int a = p0[j], bmid = p0[CWP + j], cbot = p0[2 * CWP + j];
        r1[j] = bmid;
        colsum[j] = a + bmid + cbot;
    }
    float res[4][4];
    #pragma unroll
    for (int j = 0; j < 4; j++) {
        unsigned int pk = colsum[j] + colsum[j + 1] + colsum[j + 2] - r1[j + 1];
        unsigned int pbv = pbin[j];
        float cs = 0.0f, cal[4];
        #pragma unroll
        for (int c = 0; c < 4; c++) {
            int cnt = (int)((pk  >> (4 * c)) & 0xFu);
            int bin = (int)((pbv >> (4 * c)) & 0xFu);
            float v = vf[c * 135 + cnt * 15 + bin];
            cal[c] = v; cs += v;
        }
        if (cs == 0.0f) cs = 1.0f;
        float inv = __builtin_amdgcn_rcpf(cs);
        #pragma unroll
        for (int c = 0; c < 4; c++) res[c][j] = cal[c] * inv;
    }
    float* ob = out + (size_t)b * 4 * HW + base;
    #pragma unroll
    for (int c = 0; c < 4; c++) {
        vfloat4 v;
        v.x = res[c][0]; v.y = res[c][1]; v.z = res[c][2]; v.w = res[c][3];
        __builtin_nontemporal_store(v, reinterpret_cast<vfloat4*>(ob + (size_t)c * HW));
    }
}

extern "C" void kernel_launch(void* const* d_in, const int* in_sizes, int n_in,
                              void* d_out, int out_size, void* d_ws, size_t ws_size,
                              hipStream_t stream) {
    const float* logits    = (const float*)d_in[0];
    const float* val_freqs = (const float*)d_in[1];
    float* out             = (float*)d_out;

    const size_t need = (size_t)16 * HW * sizeof(unsigned int);  // 16.8 MB packed
    if (ws_size >= need) {
        unsigned int* packed = (unsigned int*)d_ws;
        hipLaunchKernelGGL(k1_classbins, dim3(16 * HW / 1024, 1, 1), dim3(256, 1, 1),
                           0, stream, logits, packed);
        hipLaunchKernelGGL(k2_gather, dim3(128, 1, 16), dim3(256, 1, 1),
                           0, stream, packed, val_freqs, out);
    } else {
        hipLaunchKernelGGL(fused_fallback, dim3(512 / FTX, 512 / FTY, 16), dim3(256, 1, 1),
                           0, stream, logits, val_freqs, out);
    }
}